// Round 2
// baseline (2650.874 us; speedup 1.0000x reference)
//
#include <hip/hip_runtime.h>
#include <stdint.h>

#define N_USERS 100000
#define N_ITEMS 50000
#define NTOT    150000
#define DIM     64
#define NNZ     2000000
#define NHOPS   3

// ---------------- Threefry-2x32, 20 rounds (JAX-compatible) ----------------
__host__ __device__ inline void tf2x32(uint32_t k0, uint32_t k1,
                                       uint32_t x0, uint32_t x1,
                                       uint32_t& o0, uint32_t& o1) {
  uint32_t ks2 = k0 ^ k1 ^ 0x1BD11BDAu;
  x0 += k0; x1 += k1;
#define ROTL(x,r) (((x) << (r)) | ((x) >> (32 - (r))))
#define RND(r) { x0 += x1; x1 = ROTL(x1, r); x1 ^= x0; }
  RND(13) RND(15) RND(26) RND(6)
  x0 += k1;  x1 += ks2 + 1u;
  RND(17) RND(29) RND(16) RND(24)
  x0 += ks2; x1 += k0 + 2u;
  RND(13) RND(15) RND(26) RND(6)
  x0 += k0;  x1 += k1 + 3u;
  RND(17) RND(29) RND(16) RND(24)
  x0 += k1;  x1 += ks2 + 4u;
  RND(13) RND(15) RND(26) RND(6)
  x0 += ks2; x1 += k0 + 5u;
  o0 = x0; o1 = x1;
#undef RND
#undef ROTL
}

// jax_threefry_partitionable=True uniform for flat element idx
__device__ inline float tf_uniform(uint32_t k0, uint32_t k1, uint32_t idx) {
  uint32_t b1, b2;
  tf2x32(k0, k1, 0u, idx, b1, b2);
  uint32_t bits = b1 ^ b2;
  return __uint_as_float((bits >> 9) | 0x3f800000u) - 1.0f;
}

// ---------------- kernels ----------------
// out layout: [n][hop(0..3)][d] float32 (== reference stack axis=1)

// write hop0 = concat(user,item); zero hop slots 1..3
__global__ __launch_bounds__(256) void k_init(const float4* __restrict__ user,
                                              const float4* __restrict__ item,
                                              float4* __restrict__ out) {
  int idx = blockIdx.x * 256 + threadIdx.x;      // over NTOT*16 float4s
  if (idx >= NTOT * 16) return;
  int n = idx >> 4;
  float4 v = (n < N_USERS) ? user[idx] : item[idx - N_USERS * 16];
  float4 z = make_float4(0.f, 0.f, 0.f, 0.f);
  float4* o = out + (size_t)n * 64 + (idx & 15); // row n = 64 float4s, hop h at +h*16
  o[0] = v; o[16] = z; o[32] = z; o[48] = z;
}

// one wave per 64 edges: each lane does Threefry for ONE edge; then the wave
// processes its 64 edges 4-at-a-time (16-lane groups, float4 gather + atomics).
__global__ __launch_bounds__(256) void k_spmm(const float* __restrict__ vals,
                                              const int* __restrict__ rows,
                                              const int* __restrict__ cols,
                                              float* __restrict__ out,
                                              int hop, uint32_t ke0, uint32_t ke1) {
  int wave = (blockIdx.x * 256 + threadIdx.x) >> 6;
  int base = wave * 64;
  if (base >= NNZ) return;                        // NNZ % 64 == 0, clean tail
  int lane = threadIdx.x & 63;
  int e = base + lane;
  float u = tf_uniform(ke0, ke1, (uint32_t)e);
  // reference: keep iff floor(0.5 + u) == 1  <=>  (0.5f + u) >= 1.0f
  bool keep = (0.5f + u >= 1.0f);
  float v = keep ? vals[e] * 2.0f : 0.0f;         // 1/(1-EDGE_RATE) = 2
  int r = rows[e];
  int c = cols[e];

  const int g = lane >> 4;                        // edge-subgroup 0..3
  const int q = lane & 15;                        // float4 chunk 0..15
  const float* srcbase = out + (size_t)hop * 64;
  float*       dstbase = out + (size_t)(hop + 1) * 64;
#pragma unroll 4
  for (int j = 0; j < 64; j += 4) {
    int sl = j + g;
    float vj = __shfl(v, sl, 64);
    int   cj = __shfl(c, sl, 64);
    int   rj = __shfl(r, sl, 64);
    if (vj != 0.0f) {
      const float4 sv = ((const float4*)(srcbase + (size_t)cj * 256))[q];
      float* dst = dstbase + (size_t)rj * 256 + q * 4;
      atomicAdd(dst + 0, vj * sv.x);
      atomicAdd(dst + 1, vj * sv.y);
      atomicAdd(dst + 2, vj * sv.z);
      atomicAdd(dst + 3, vj * sv.w);
    }
  }
}

// inverted message dropout, in place on hop+1 slice
__global__ __launch_bounds__(256) void k_mdrop(float* __restrict__ out,
                                               int hop, uint32_t km0, uint32_t km1) {
  int idx = blockIdx.x * 256 + threadIdx.x;      // flat over (NTOT, DIM)
  if (idx >= NTOT * DIM) return;
  float u = tf_uniform(km0, km1, (uint32_t)idx);
  int n = idx >> 6, d = idx & 63;
  float* p = out + ((size_t)n * 4 + hop + 1) * 64 + d;
  float val = *p;
  *p = (u < 0.9f) ? val * (float)(1.0 / 0.9) : 0.0f;
}

// ---------------- launch ----------------
extern "C" void kernel_launch(void* const* d_in, const int* in_sizes, int n_in,
                              void* d_out, int out_size, void* d_ws, size_t ws_size,
                              hipStream_t stream) {
  const float* user = (const float*)d_in[0];
  const float* item = (const float*)d_in[1];
  const float* vals = (const float*)d_in[2];
  const int*   rows = (const int*)d_in[3];
  const int*   cols = (const int*)d_in[4];
  float* out = (float*)d_out;

  // host-side key schedule: key(42) -> per-hop (dkey, ke, km) via fold-like split
  uint32_t k0 = 0u, k1 = 42u;
  uint32_t ke[NHOPS][2], km[NHOPS][2];
  for (int h = 0; h < NHOPS; ++h) {
    uint32_t nk0, nk1;
    tf2x32(k0, k1, 0u, 0u, nk0, nk1);           // keys[0] -> new dkey
    tf2x32(k0, k1, 0u, 1u, ke[h][0], ke[h][1]); // keys[1] -> edge-dropout key
    tf2x32(k0, k1, 0u, 2u, km[h][0], km[h][1]); // keys[2] -> message-dropout key
    k0 = nk0; k1 = nk1;
  }

  k_init<<<(NTOT * 16 + 255) / 256, 256, 0, stream>>>(
      (const float4*)user, (const float4*)item, (float4*)out);

  for (int h = 0; h < NHOPS; ++h) {
    k_spmm<<<(NNZ / 64 * 64 + 255) / 256, 256, 0, stream>>>(vals, rows, cols, out, h,
                                                            ke[h][0], ke[h][1]);
    k_mdrop<<<(NTOT * DIM + 255) / 256, 256, 0, stream>>>(out, h,
                                                          km[h][0], km[h][1]);
  }
}

// Round 3
// 780.252 us; speedup vs baseline: 3.3975x; 3.3975x over previous
//
#include <hip/hip_runtime.h>
#include <stdint.h>

#define N_USERS 100000
#define N_ITEMS 50000
#define NTOT    150000
#define DIM     64
#define NNZ     2000000
#define NHOPS   3
#define NBLK_SCAN ((NTOT + 255) / 256)   // 587

// ---------------- Threefry-2x32, 20 rounds (JAX-compatible) ----------------
__host__ __device__ inline void tf2x32(uint32_t k0, uint32_t k1,
                                       uint32_t x0, uint32_t x1,
                                       uint32_t& o0, uint32_t& o1) {
  uint32_t ks2 = k0 ^ k1 ^ 0x1BD11BDAu;
  x0 += k0; x1 += k1;
#define ROTL(x,r) (((x) << (r)) | ((x) >> (32 - (r))))
#define RND(r) { x0 += x1; x1 = ROTL(x1, r); x1 ^= x0; }
  RND(13) RND(15) RND(26) RND(6)
  x0 += k1;  x1 += ks2 + 1u;
  RND(17) RND(29) RND(16) RND(24)
  x0 += ks2; x1 += k0 + 2u;
  RND(13) RND(15) RND(26) RND(6)
  x0 += k0;  x1 += k1 + 3u;
  RND(17) RND(29) RND(16) RND(24)
  x0 += k1;  x1 += ks2 + 4u;
  RND(13) RND(15) RND(26) RND(6)
  x0 += ks2; x1 += k0 + 5u;
  o0 = x0; o1 = x1;
#undef RND
#undef ROTL
}

__device__ inline float tf_uniform(uint32_t k0, uint32_t k1, uint32_t idx) {
  uint32_t b1, b2;
  tf2x32(k0, k1, 0u, idx, b1, b2);
  uint32_t bits = b1 ^ b2;
  return __uint_as_float((bits >> 9) | 0x3f800000u) - 1.0f;
}

// ---------------- kernels ----------------
// out layout: [n][hop(0..3)][d] float32. Row stride = 256 floats.

// hop0 = concat(user,item). Hop slices 1..3 are fully written by k_spmm_seg.
__global__ __launch_bounds__(256) void k_init(const float4* __restrict__ user,
                                              const float4* __restrict__ item,
                                              float4* __restrict__ out) {
  int idx = blockIdx.x * 256 + threadIdx.x;      // over NTOT*16 float4s
  if (idx >= NTOT * 16) return;
  int n = idx >> 4;
  float4 v = (n < N_USERS) ? user[idx] : item[idx - N_USERS * 16];
  out[(size_t)n * 64 + (idx & 15)] = v;
}

// histogram of row degrees
__global__ __launch_bounds__(256) void k_hist(const int* __restrict__ rows,
                                              uint32_t* __restrict__ cnt) {
  int e = blockIdx.x * 256 + threadIdx.x;
  if (e >= NNZ) return;
  atomicAdd(&cnt[rows[e]], 1u);
}

// block-level exclusive scan (256-wide) + block totals
__global__ __launch_bounds__(256) void k_scan1(const uint32_t* __restrict__ cnt,
                                               uint32_t* __restrict__ strt,
                                               uint32_t* __restrict__ part) {
  __shared__ uint32_t s[256];
  int t = threadIdx.x;
  int i = blockIdx.x * 256 + t;
  uint32_t x = (i < NTOT) ? cnt[i] : 0u;
  s[t] = x; __syncthreads();
  for (int off = 1; off < 256; off <<= 1) {
    uint32_t y = (t >= off) ? s[t - off] : 0u;
    __syncthreads();
    s[t] += y;
    __syncthreads();
  }
  if (i < NTOT) strt[i] = s[t] - x;              // exclusive
  if (t == 255) part[blockIdx.x] = s[255];       // block total
}

// exclusive scan of the 587 block totals (single block)
__global__ __launch_bounds__(1024) void k_scan2(uint32_t* __restrict__ part) {
  __shared__ uint32_t s[1024];
  int t = threadIdx.x;
  uint32_t x = (t < NBLK_SCAN) ? part[t] : 0u;
  s[t] = x; __syncthreads();
  for (int off = 1; off < 1024; off <<= 1) {
    uint32_t y = (t >= off) ? s[t - off] : 0u;
    __syncthreads();
    s[t] += y;
    __syncthreads();
  }
  if (t < NBLK_SCAN) part[t] = s[t] - x;         // exclusive
}

// add block offsets; init per-row scatter cursors
__global__ __launch_bounds__(256) void k_scan3(uint32_t* __restrict__ strt,
                                               const uint32_t* __restrict__ part,
                                               uint32_t* __restrict__ cur) {
  int i = blockIdx.x * 256 + threadIdx.x;
  if (i >= NTOT) return;
  uint32_t v = strt[i] + part[i >> 8];
  strt[i] = v;
  cur[i] = v;
}

// scatter edges into row-sorted order; precompute all 3 hops' dropout-scaled vals
__global__ __launch_bounds__(256) void k_scatter(const float* __restrict__ vals,
                                                 const int* __restrict__ rows,
                                                 const int* __restrict__ cols,
                                                 uint32_t* __restrict__ cur,
                                                 int* __restrict__ scol,
                                                 float* __restrict__ sv0,
                                                 float* __restrict__ sv1,
                                                 float* __restrict__ sv2,
                                                 uint32_t e00, uint32_t e01,
                                                 uint32_t e10, uint32_t e11,
                                                 uint32_t e20, uint32_t e21) {
  int e = blockIdx.x * 256 + threadIdx.x;
  if (e >= NNZ) return;
  float val2 = vals[e] * 2.0f;                   // 1/(1-EDGE_RATE) = 2
  float u0 = tf_uniform(e00, e01, (uint32_t)e);
  float u1 = tf_uniform(e10, e11, (uint32_t)e);
  float u2 = tf_uniform(e20, e21, (uint32_t)e);
  float v0 = (0.5f + u0 >= 1.0f) ? val2 : 0.0f;  // match reference fp exactly
  float v1 = (0.5f + u1 >= 1.0f) ? val2 : 0.0f;
  float v2 = (0.5f + u2 >= 1.0f) ? val2 : 0.0f;
  uint32_t j = atomicAdd(&cur[rows[e]], 1u);
  scol[j] = cols[e];
  sv0[j] = v0; sv1[j] = v1; sv2[j] = v2;
}

// segmented SpMM: one wave per row, lane = dim. Fused message dropout.
__global__ __launch_bounds__(256) void k_spmm_seg(const uint32_t* __restrict__ strt,
                                                  const uint32_t* __restrict__ cnt,
                                                  const int* __restrict__ scol,
                                                  const float* __restrict__ svh,
                                                  float* __restrict__ out,
                                                  int hop, uint32_t km0, uint32_t km1) {
  int wid = (blockIdx.x * 256 + threadIdx.x) >> 6;   // row id
  if (wid >= NTOT) return;
  int lane = threadIdx.x & 63;
  uint32_t s = strt[wid];
  uint32_t d = cnt[wid];
  const float* srcbase = out + (size_t)hop * 64 + lane;  // + c*256 per edge
  float acc = 0.0f;
  for (uint32_t j = s; j < s + d; ++j) {
    float vj = svh[j];
    int   cj = scol[j];
    if (vj != 0.0f) acc += vj * srcbase[(size_t)cj * 256];
  }
  // message dropout (inverted, keep iff u < 0.9), flat index over (NTOT, DIM)
  float u = tf_uniform(km0, km1, (uint32_t)(wid * 64 + lane));
  acc = (u < 0.9f) ? acc * (float)(1.0 / 0.9) : 0.0f;
  out[((size_t)wid * 4 + hop + 1) * 64 + lane] = acc;
}

// ---------------- launch ----------------
extern "C" void kernel_launch(void* const* d_in, const int* in_sizes, int n_in,
                              void* d_out, int out_size, void* d_ws, size_t ws_size,
                              hipStream_t stream) {
  const float* user = (const float*)d_in[0];
  const float* item = (const float*)d_in[1];
  const float* vals = (const float*)d_in[2];
  const int*   rows = (const int*)d_in[3];
  const int*   cols = (const int*)d_in[4];
  float* out = (float*)d_out;

  // workspace layout (~34 MB)
  uint32_t* cnt  = (uint32_t*)d_ws;        // NTOT
  uint32_t* strt = cnt + NTOT;             // NTOT
  uint32_t* cur  = strt + NTOT;            // NTOT
  uint32_t* part = cur + NTOT;             // 1024 (pad)
  int*      scol = (int*)(part + 1024);    // NNZ
  float*    sv0  = (float*)(scol + NNZ);   // NNZ
  float*    sv1  = sv0 + NNZ;              // NNZ
  float*    sv2  = sv1 + NNZ;              // NNZ

  // host-side key schedule: key(42) -> per-hop (dkey, ke, km)
  uint32_t k0 = 0u, k1 = 42u;
  uint32_t ke[NHOPS][2], km[NHOPS][2];
  for (int h = 0; h < NHOPS; ++h) {
    uint32_t nk0, nk1;
    tf2x32(k0, k1, 0u, 0u, nk0, nk1);
    tf2x32(k0, k1, 0u, 1u, ke[h][0], ke[h][1]);
    tf2x32(k0, k1, 0u, 2u, km[h][0], km[h][1]);
    k0 = nk0; k1 = nk1;
  }

  hipMemsetAsync(cnt, 0, NTOT * sizeof(uint32_t), stream);
  k_hist<<<(NNZ + 255) / 256, 256, 0, stream>>>(rows, cnt);
  k_scan1<<<NBLK_SCAN, 256, 0, stream>>>(cnt, strt, part);
  k_scan2<<<1, 1024, 0, stream>>>(part);
  k_scan3<<<NBLK_SCAN, 256, 0, stream>>>(strt, part, cur);
  k_scatter<<<(NNZ + 255) / 256, 256, 0, stream>>>(vals, rows, cols, cur,
                                                   scol, sv0, sv1, sv2,
                                                   ke[0][0], ke[0][1],
                                                   ke[1][0], ke[1][1],
                                                   ke[2][0], ke[2][1]);
  k_init<<<(NTOT * 16 + 255) / 256, 256, 0, stream>>>(
      (const float4*)user, (const float4*)item, (float4*)out);

  const float* svh[NHOPS] = {sv0, sv1, sv2};
  for (int h = 0; h < NHOPS; ++h) {
    k_spmm_seg<<<(NTOT * 64) / 256, 256, 0, stream>>>(strt, cnt, scol, svh[h],
                                                      out, h, km[h][0], km[h][1]);
  }
}

// Round 4
// 554.335 us; speedup vs baseline: 4.7821x; 1.4075x over previous
//
#include <hip/hip_runtime.h>
#include <stdint.h>

#define N_USERS 100000
#define N_ITEMS 50000
#define NTOT    150000
#define DIM     64
#define NNZ     2000000
#define NHOPS   3
#define NBLK_SCAN ((NTOT + 255) / 256)   // 587

// ---------------- Threefry-2x32, 20 rounds (JAX-compatible) ----------------
__host__ __device__ inline void tf2x32(uint32_t k0, uint32_t k1,
                                       uint32_t x0, uint32_t x1,
                                       uint32_t& o0, uint32_t& o1) {
  uint32_t ks2 = k0 ^ k1 ^ 0x1BD11BDAu;
  x0 += k0; x1 += k1;
#define ROTL(x,r) (((x) << (r)) | ((x) >> (32 - (r))))
#define RND(r) { x0 += x1; x1 = ROTL(x1, r); x1 ^= x0; }
  RND(13) RND(15) RND(26) RND(6)
  x0 += k1;  x1 += ks2 + 1u;
  RND(17) RND(29) RND(16) RND(24)
  x0 += ks2; x1 += k0 + 2u;
  RND(13) RND(15) RND(26) RND(6)
  x0 += k0;  x1 += k1 + 3u;
  RND(17) RND(29) RND(16) RND(24)
  x0 += k1;  x1 += ks2 + 4u;
  RND(13) RND(15) RND(26) RND(6)
  x0 += ks2; x1 += k0 + 5u;
  o0 = x0; o1 = x1;
#undef RND
#undef ROTL
}

__device__ inline float tf_uniform(uint32_t k0, uint32_t k1, uint32_t idx) {
  uint32_t b1, b2;
  tf2x32(k0, k1, 0u, idx, b1, b2);
  uint32_t bits = b1 ^ b2;
  return __uint_as_float((bits >> 9) | 0x3f800000u) - 1.0f;
}

// ---------------- kernels ----------------
// out layout: [n][hop(0..3)][d] float32. Row stride = 256 floats.

// hop0 = concat(user,item). Hop slices 1..3 are fully written by k_spmm_seg.
__global__ __launch_bounds__(256) void k_init(const float4* __restrict__ user,
                                              const float4* __restrict__ item,
                                              float4* __restrict__ out) {
  int idx = blockIdx.x * 256 + threadIdx.x;      // over NTOT*16 float4s
  if (idx >= NTOT * 16) return;
  int n = idx >> 4;
  float4 v = (n < N_USERS) ? user[idx] : item[idx - N_USERS * 16];
  out[(size_t)n * 64 + (idx & 15)] = v;
}

// histogram of row degrees
__global__ __launch_bounds__(256) void k_hist(const int* __restrict__ rows,
                                              uint32_t* __restrict__ cnt) {
  int e = blockIdx.x * 256 + threadIdx.x;
  if (e >= NNZ) return;
  atomicAdd(&cnt[rows[e]], 1u);
}

// block-level exclusive scan (256-wide) + block totals
__global__ __launch_bounds__(256) void k_scan1(const uint32_t* __restrict__ cnt,
                                               uint32_t* __restrict__ strt,
                                               uint32_t* __restrict__ part) {
  __shared__ uint32_t s[256];
  int t = threadIdx.x;
  int i = blockIdx.x * 256 + t;
  uint32_t x = (i < NTOT) ? cnt[i] : 0u;
  s[t] = x; __syncthreads();
  for (int off = 1; off < 256; off <<= 1) {
    uint32_t y = (t >= off) ? s[t - off] : 0u;
    __syncthreads();
    s[t] += y;
    __syncthreads();
  }
  if (i < NTOT) strt[i] = s[t] - x;              // exclusive
  if (t == 255) part[blockIdx.x] = s[255];       // block total
}

// exclusive scan of the 587 block totals (single block)
__global__ __launch_bounds__(1024) void k_scan2(uint32_t* __restrict__ part) {
  __shared__ uint32_t s[1024];
  int t = threadIdx.x;
  uint32_t x = (t < NBLK_SCAN) ? part[t] : 0u;
  s[t] = x; __syncthreads();
  for (int off = 1; off < 1024; off <<= 1) {
    uint32_t y = (t >= off) ? s[t - off] : 0u;
    __syncthreads();
    s[t] += y;
    __syncthreads();
  }
  if (t < NBLK_SCAN) part[t] = s[t] - x;         // exclusive
}

// add block offsets; init per-row scatter cursors
__global__ __launch_bounds__(256) void k_scan3(uint32_t* __restrict__ strt,
                                               const uint32_t* __restrict__ part,
                                               uint32_t* __restrict__ cur) {
  int i = blockIdx.x * 256 + threadIdx.x;
  if (i >= NTOT) return;
  uint32_t v = strt[i] + part[i >> 8];
  strt[i] = v;
  cur[i] = v;
}

// scatter edges into row-sorted order as ONE packed 8B record per edge:
//   rec.x = col<<3 | keep0 | keep1<<1 | keep2<<2,  rec.y = bits(val*2)
__global__ __launch_bounds__(256) void k_scatter(const float* __restrict__ vals,
                                                 const int* __restrict__ rows,
                                                 const int* __restrict__ cols,
                                                 uint32_t* __restrict__ cur,
                                                 uint2* __restrict__ rec,
                                                 uint32_t e00, uint32_t e01,
                                                 uint32_t e10, uint32_t e11,
                                                 uint32_t e20, uint32_t e21) {
  int e = blockIdx.x * 256 + threadIdx.x;
  if (e >= NNZ) return;
  float val2 = vals[e] * 2.0f;                   // 1/(1-EDGE_RATE) = 2
  uint32_t kb = 0u;                              // match reference fp exactly
  if (0.5f + tf_uniform(e00, e01, (uint32_t)e) >= 1.0f) kb |= 1u;
  if (0.5f + tf_uniform(e10, e11, (uint32_t)e) >= 1.0f) kb |= 2u;
  if (0.5f + tf_uniform(e20, e21, (uint32_t)e) >= 1.0f) kb |= 4u;
  uint32_t j = atomicAdd(&cur[rows[e]], 1u);
  rec[j] = make_uint2(((uint32_t)cols[e] << 3) | kb, __float_as_uint(val2));
}

// segmented SpMM: one wave per row, lane = dim. Unroll-4, branchless
// (dropped edges gather row 0 with v=0). Fused message dropout.
__global__ __launch_bounds__(256) void k_spmm_seg(const uint32_t* __restrict__ strt,
                                                  const uint32_t* __restrict__ cnt,
                                                  const uint2* __restrict__ rec,
                                                  float* __restrict__ out,
                                                  int hop, uint32_t km0, uint32_t km1) {
  int wid = (blockIdx.x * 256 + threadIdx.x) >> 6;   // row id
  if (wid >= NTOT) return;
  int lane = threadIdx.x & 63;
  uint32_t s = strt[wid];
  uint32_t e = s + cnt[wid];
  const uint32_t mask = 1u << hop;
  const float* srcbase = out + (size_t)hop * 64 + lane;  // + c*256 per edge
  float a0 = 0.f, a1 = 0.f, a2 = 0.f, a3 = 0.f;
  uint32_t j = s;
  for (; j + 4 <= e; j += 4) {
    uint2 r0 = rec[j], r1 = rec[j + 1], r2 = rec[j + 2], r3 = rec[j + 3];
    bool k0 = (r0.x & mask) != 0u, k1 = (r1.x & mask) != 0u;
    bool k2 = (r2.x & mask) != 0u, k3 = (r3.x & mask) != 0u;
    size_t c0 = k0 ? (size_t)(r0.x >> 3) * 256 : 0;
    size_t c1 = k1 ? (size_t)(r1.x >> 3) * 256 : 0;
    size_t c2 = k2 ? (size_t)(r2.x >> 3) * 256 : 0;
    size_t c3 = k3 ? (size_t)(r3.x >> 3) * 256 : 0;
    float v0 = k0 ? __uint_as_float(r0.y) : 0.f;
    float v1 = k1 ? __uint_as_float(r1.y) : 0.f;
    float v2 = k2 ? __uint_as_float(r2.y) : 0.f;
    float v3 = k3 ? __uint_as_float(r3.y) : 0.f;
    a0 += v0 * srcbase[c0];
    a1 += v1 * srcbase[c1];
    a2 += v2 * srcbase[c2];
    a3 += v3 * srcbase[c3];
  }
  for (; j < e; ++j) {
    uint2 r = rec[j];
    if (r.x & mask) a0 += __uint_as_float(r.y) * srcbase[(size_t)(r.x >> 3) * 256];
  }
  float acc = (a0 + a1) + (a2 + a3);
  // message dropout (inverted, keep iff u < 0.9), flat index over (NTOT, DIM)
  float u = tf_uniform(km0, km1, (uint32_t)(wid * 64 + lane));
  acc = (u < 0.9f) ? acc * (float)(1.0 / 0.9) : 0.0f;
  out[((size_t)wid * 4 + hop + 1) * 64 + lane] = acc;
}

// ---------------- launch ----------------
extern "C" void kernel_launch(void* const* d_in, const int* in_sizes, int n_in,
                              void* d_out, int out_size, void* d_ws, size_t ws_size,
                              hipStream_t stream) {
  const float* user = (const float*)d_in[0];
  const float* item = (const float*)d_in[1];
  const float* vals = (const float*)d_in[2];
  const int*   rows = (const int*)d_in[3];
  const int*   cols = (const int*)d_in[4];
  float* out = (float*)d_out;

  // workspace layout (~18 MB)
  uint32_t* cnt  = (uint32_t*)d_ws;        // NTOT
  uint32_t* strt = cnt + NTOT;             // NTOT
  uint32_t* cur  = strt + NTOT;            // NTOT
  uint32_t* part = cur + NTOT;             // 1024 (pad)
  uint2*    rec  = (uint2*)(part + 1024);  // NNZ * 8B

  // host-side key schedule: key(42) -> per-hop (dkey, ke, km)
  uint32_t k0 = 0u, k1 = 42u;
  uint32_t ke[NHOPS][2], km[NHOPS][2];
  for (int h = 0; h < NHOPS; ++h) {
    uint32_t nk0, nk1;
    tf2x32(k0, k1, 0u, 0u, nk0, nk1);
    tf2x32(k0, k1, 0u, 1u, ke[h][0], ke[h][1]);
    tf2x32(k0, k1, 0u, 2u, km[h][0], km[h][1]);
    k0 = nk0; k1 = nk1;
  }

  hipMemsetAsync(cnt, 0, NTOT * sizeof(uint32_t), stream);
  k_hist<<<(NNZ + 255) / 256, 256, 0, stream>>>(rows, cnt);
  k_scan1<<<NBLK_SCAN, 256, 0, stream>>>(cnt, strt, part);
  k_scan2<<<1, 1024, 0, stream>>>(part);
  k_scan3<<<NBLK_SCAN, 256, 0, stream>>>(strt, part, cur);
  k_scatter<<<(NNZ + 255) / 256, 256, 0, stream>>>(vals, rows, cols, cur, rec,
                                                   ke[0][0], ke[0][1],
                                                   ke[1][0], ke[1][1],
                                                   ke[2][0], ke[2][1]);
  k_init<<<(NTOT * 16 + 255) / 256, 256, 0, stream>>>(
      (const float4*)user, (const float4*)item, (float4*)out);

  for (int h = 0; h < NHOPS; ++h) {
    k_spmm_seg<<<(NTOT * 64) / 256, 256, 0, stream>>>(strt, cnt, rec,
                                                      out, h, km[h][0], km[h][1]);
  }
}

// Round 5
// 388.395 us; speedup vs baseline: 6.8252x; 1.4272x over previous
//
#include <hip/hip_runtime.h>
#include <stdint.h>

#define N_USERS 100000
#define N_ITEMS 50000
#define NTOT    150000
#define DIM     64
#define NNZ     2000000
#define NHOPS   3
#define NBLK_SCAN ((NTOT + 255) / 256)   // 587

// ---------------- Threefry-2x32, 20 rounds (JAX-compatible) ----------------
__host__ __device__ inline void tf2x32(uint32_t k0, uint32_t k1,
                                       uint32_t x0, uint32_t x1,
                                       uint32_t& o0, uint32_t& o1) {
  uint32_t ks2 = k0 ^ k1 ^ 0x1BD11BDAu;
  x0 += k0; x1 += k1;
#define ROTL(x,r) (((x) << (r)) | ((x) >> (32 - (r))))
#define RND(r) { x0 += x1; x1 = ROTL(x1, r); x1 ^= x0; }
  RND(13) RND(15) RND(26) RND(6)
  x0 += k1;  x1 += ks2 + 1u;
  RND(17) RND(29) RND(16) RND(24)
  x0 += ks2; x1 += k0 + 2u;
  RND(13) RND(15) RND(26) RND(6)
  x0 += k0;  x1 += k1 + 3u;
  RND(17) RND(29) RND(16) RND(24)
  x0 += k1;  x1 += ks2 + 4u;
  RND(13) RND(15) RND(26) RND(6)
  x0 += ks2; x1 += k0 + 5u;
  o0 = x0; o1 = x1;
#undef RND
#undef ROTL
}

__device__ inline float tf_uniform(uint32_t k0, uint32_t k1, uint32_t idx) {
  uint32_t b1, b2;
  tf2x32(k0, k1, 0u, idx, b1, b2);
  uint32_t bits = b1 ^ b2;
  return __uint_as_float((bits >> 9) | 0x3f800000u) - 1.0f;
}

__device__ inline uint32_t keep_bits(uint32_t e,
                                     uint32_t e00, uint32_t e01,
                                     uint32_t e10, uint32_t e11,
                                     uint32_t e20, uint32_t e21) {
  uint32_t kb = 0u;                              // match reference fp exactly
  if (0.5f + tf_uniform(e00, e01, e) >= 1.0f) kb |= 1u;
  if (0.5f + tf_uniform(e10, e11, e) >= 1.0f) kb |= 2u;
  if (0.5f + tf_uniform(e20, e21, e) >= 1.0f) kb |= 4u;
  return kb;
}

// ---------------- kernels ----------------
// out layout: [n][hop(0..3)][d] float32. Row stride = 256 floats.

// hop0 = concat(user,item). Hop slices 1..3 are fully written by k_spmm_seg.
__global__ __launch_bounds__(256) void k_init(const float4* __restrict__ user,
                                              const float4* __restrict__ item,
                                              float4* __restrict__ out) {
  int idx = blockIdx.x * 256 + threadIdx.x;      // over NTOT*16 float4s
  if (idx >= NTOT * 16) return;
  int n = idx >> 4;
  float4 v = (n < N_USERS) ? user[idx] : item[idx - N_USERS * 16];
  out[(size_t)n * 64 + (idx & 15)] = v;
}

// histogram of row degrees, counting ONLY edges kept in >=1 hop
__global__ __launch_bounds__(256) void k_hist(const int* __restrict__ rows,
                                              uint32_t* __restrict__ cnt,
                                              uint32_t e00, uint32_t e01,
                                              uint32_t e10, uint32_t e11,
                                              uint32_t e20, uint32_t e21) {
  int e = blockIdx.x * 256 + threadIdx.x;
  if (e >= NNZ) return;
  uint32_t kb = keep_bits((uint32_t)e, e00, e01, e10, e11, e20, e21);
  if (kb) atomicAdd(&cnt[rows[e]], 1u);
}

// block-level exclusive scan (256-wide) + block totals
__global__ __launch_bounds__(256) void k_scan1(const uint32_t* __restrict__ cnt,
                                               uint32_t* __restrict__ strt,
                                               uint32_t* __restrict__ part) {
  __shared__ uint32_t s[256];
  int t = threadIdx.x;
  int i = blockIdx.x * 256 + t;
  uint32_t x = (i < NTOT) ? cnt[i] : 0u;
  s[t] = x; __syncthreads();
  for (int off = 1; off < 256; off <<= 1) {
    uint32_t y = (t >= off) ? s[t - off] : 0u;
    __syncthreads();
    s[t] += y;
    __syncthreads();
  }
  if (i < NTOT) strt[i] = s[t] - x;              // exclusive
  if (t == 255) part[blockIdx.x] = s[255];       // block total
}

// exclusive scan of the 587 block totals (single block)
__global__ __launch_bounds__(1024) void k_scan2(uint32_t* __restrict__ part) {
  __shared__ uint32_t s[1024];
  int t = threadIdx.x;
  uint32_t x = (t < NBLK_SCAN) ? part[t] : 0u;
  s[t] = x; __syncthreads();
  for (int off = 1; off < 1024; off <<= 1) {
    uint32_t y = (t >= off) ? s[t - off] : 0u;
    __syncthreads();
    s[t] += y;
    __syncthreads();
  }
  if (t < NBLK_SCAN) part[t] = s[t] - x;         // exclusive
}

// add block offsets; init per-row scatter cursors
__global__ __launch_bounds__(256) void k_scan3(uint32_t* __restrict__ strt,
                                               const uint32_t* __restrict__ part,
                                               uint32_t* __restrict__ cur) {
  int i = blockIdx.x * 256 + threadIdx.x;
  if (i >= NTOT) return;
  uint32_t v = strt[i] + part[i >> 8];
  strt[i] = v;
  cur[i] = v;
}

// scatter kept edges into row-sorted order as ONE packed 8B record per edge:
//   rec.x = col<<3 | keep0 | keep1<<1 | keep2<<2,  rec.y = bits(val*2)
__global__ __launch_bounds__(256) void k_scatter(const float* __restrict__ vals,
                                                 const int* __restrict__ rows,
                                                 const int* __restrict__ cols,
                                                 uint32_t* __restrict__ cur,
                                                 uint2* __restrict__ rec,
                                                 uint32_t e00, uint32_t e01,
                                                 uint32_t e10, uint32_t e11,
                                                 uint32_t e20, uint32_t e21) {
  int e = blockIdx.x * 256 + threadIdx.x;
  if (e >= NNZ) return;
  uint32_t kb = keep_bits((uint32_t)e, e00, e01, e10, e11, e20, e21);
  if (!kb) return;
  float val2 = vals[e] * 2.0f;                   // 1/(1-EDGE_RATE) = 2
  uint32_t j = atomicAdd(&cur[rows[e]], 1u);
  rec[j] = make_uint2(((uint32_t)cols[e] << 3) | kb, __float_as_uint(val2));
}

// segmented SpMM: one WAVE per 4 rows; 16 lanes x float4 per row.
// 4 independent row-chains x unroll-4 = up to 16 outstanding gathers/wave.
// Dropped-this-hop edges gather row 0 (L1-hot) with v=0. Fused message dropout.
__global__ __launch_bounds__(256) void k_spmm_seg(const uint32_t* __restrict__ strt,
                                                  const uint32_t* __restrict__ cnt,
                                                  const uint2* __restrict__ rec,
                                                  float* __restrict__ out,
                                                  int hop, uint32_t km0, uint32_t km1) {
  int wave = (blockIdx.x * 256 + threadIdx.x) >> 6;
  int lane = threadIdx.x & 63;
  int g = lane >> 4;                 // row subgroup 0..3
  int q = lane & 15;                 // float4 chunk 0..15
  int row = wave * 4 + g;
  if (row >= NTOT) return;
  uint32_t s = strt[row];
  uint32_t e = s + cnt[row];
  const uint32_t mask = 1u << hop;
  // src row c, float4 chunk q lives at float4 index c*64 + hop*16 + q
  const float4* srcb = (const float4*)out + (size_t)hop * 16 + q;
  float4 a0 = {0.f,0.f,0.f,0.f}, a1 = a0, a2 = a0, a3 = a0;
  uint32_t j = s;
  for (; j + 4 <= e; j += 4) {
    uint2 r0 = rec[j], r1 = rec[j + 1], r2 = rec[j + 2], r3 = rec[j + 3];
    bool k0 = (r0.x & mask) != 0u, k1 = (r1.x & mask) != 0u;
    bool k2 = (r2.x & mask) != 0u, k3 = (r3.x & mask) != 0u;
    size_t c0 = k0 ? (size_t)(r0.x >> 3) * 64 : 0;
    size_t c1 = k1 ? (size_t)(r1.x >> 3) * 64 : 0;
    size_t c2 = k2 ? (size_t)(r2.x >> 3) * 64 : 0;
    size_t c3 = k3 ? (size_t)(r3.x >> 3) * 64 : 0;
    float4 s0 = srcb[c0], s1 = srcb[c1], s2 = srcb[c2], s3 = srcb[c3];
    float v0 = k0 ? __uint_as_float(r0.y) : 0.f;
    float v1 = k1 ? __uint_as_float(r1.y) : 0.f;
    float v2 = k2 ? __uint_as_float(r2.y) : 0.f;
    float v3 = k3 ? __uint_as_float(r3.y) : 0.f;
    a0.x += v0 * s0.x; a0.y += v0 * s0.y; a0.z += v0 * s0.z; a0.w += v0 * s0.w;
    a1.x += v1 * s1.x; a1.y += v1 * s1.y; a1.z += v1 * s1.z; a1.w += v1 * s1.w;
    a2.x += v2 * s2.x; a2.y += v2 * s2.y; a2.z += v2 * s2.z; a2.w += v2 * s2.w;
    a3.x += v3 * s3.x; a3.y += v3 * s3.y; a3.z += v3 * s3.z; a3.w += v3 * s3.w;
  }
  for (; j < e; ++j) {
    uint2 r = rec[j];
    if (r.x & mask) {
      float v = __uint_as_float(r.y);
      float4 sv = srcb[(size_t)(r.x >> 3) * 64];
      a0.x += v * sv.x; a0.y += v * sv.y; a0.z += v * sv.z; a0.w += v * sv.w;
    }
  }
  float4 acc;
  acc.x = (a0.x + a1.x) + (a2.x + a3.x);
  acc.y = (a0.y + a1.y) + (a2.y + a3.y);
  acc.z = (a0.z + a1.z) + (a2.z + a3.z);
  acc.w = (a0.w + a1.w) + (a2.w + a3.w);
  // message dropout (inverted, keep iff u < 0.9), flat index over (NTOT, DIM)
  uint32_t base = (uint32_t)(row * 64 + q * 4);
  float u0 = tf_uniform(km0, km1, base + 0u);
  float u1 = tf_uniform(km0, km1, base + 1u);
  float u2 = tf_uniform(km0, km1, base + 2u);
  float u3 = tf_uniform(km0, km1, base + 3u);
  const float sc = (float)(1.0 / 0.9);
  acc.x = (u0 < 0.9f) ? acc.x * sc : 0.0f;
  acc.y = (u1 < 0.9f) ? acc.y * sc : 0.0f;
  acc.z = (u2 < 0.9f) ? acc.z * sc : 0.0f;
  acc.w = (u3 < 0.9f) ? acc.w * sc : 0.0f;
  ((float4*)(out + ((size_t)row * 4 + hop + 1) * 64))[q] = acc;
}

// ---------------- launch ----------------
extern "C" void kernel_launch(void* const* d_in, const int* in_sizes, int n_in,
                              void* d_out, int out_size, void* d_ws, size_t ws_size,
                              hipStream_t stream) {
  const float* user = (const float*)d_in[0];
  const float* item = (const float*)d_in[1];
  const float* vals = (const float*)d_in[2];
  const int*   rows = (const int*)d_in[3];
  const int*   cols = (const int*)d_in[4];
  float* out = (float*)d_out;

  // workspace layout (~18 MB)
  uint32_t* cnt  = (uint32_t*)d_ws;        // NTOT
  uint32_t* strt = cnt + NTOT;             // NTOT
  uint32_t* cur  = strt + NTOT;            // NTOT
  uint32_t* part = cur + NTOT;             // 1024 (pad)
  uint2*    rec  = (uint2*)(part + 1024);  // <= NNZ * 8B

  // host-side key schedule: key(42) -> per-hop (dkey, ke, km)
  uint32_t k0 = 0u, k1 = 42u;
  uint32_t ke[NHOPS][2], km[NHOPS][2];
  for (int h = 0; h < NHOPS; ++h) {
    uint32_t nk0, nk1;
    tf2x32(k0, k1, 0u, 0u, nk0, nk1);
    tf2x32(k0, k1, 0u, 1u, ke[h][0], ke[h][1]);
    tf2x32(k0, k1, 0u, 2u, km[h][0], km[h][1]);
    k0 = nk0; k1 = nk1;
  }

  hipMemsetAsync(cnt, 0, NTOT * sizeof(uint32_t), stream);
  k_hist<<<(NNZ + 255) / 256, 256, 0, stream>>>(rows, cnt,
                                                ke[0][0], ke[0][1],
                                                ke[1][0], ke[1][1],
                                                ke[2][0], ke[2][1]);
  k_scan1<<<NBLK_SCAN, 256, 0, stream>>>(cnt, strt, part);
  k_scan2<<<1, 1024, 0, stream>>>(part);
  k_scan3<<<NBLK_SCAN, 256, 0, stream>>>(strt, part, cur);
  k_scatter<<<(NNZ + 255) / 256, 256, 0, stream>>>(vals, rows, cols, cur, rec,
                                                   ke[0][0], ke[0][1],
                                                   ke[1][0], ke[1][1],
                                                   ke[2][0], ke[2][1]);
  k_init<<<(NTOT * 16 + 255) / 256, 256, 0, stream>>>(
      (const float4*)user, (const float4*)item, (float4*)out);

  for (int h = 0; h < NHOPS; ++h) {
    k_spmm_seg<<<((NTOT + 3) / 4 * 64 + 255) / 256, 256, 0, stream>>>(
        strt, cnt, rec, out, h, km[h][0], km[h][1]);
  }
}

// Round 6
// 335.835 us; speedup vs baseline: 7.8934x; 1.1565x over previous
//
#include <hip/hip_runtime.h>
#include <stdint.h>

#define N_USERS 100000
#define N_ITEMS 50000
#define NTOT    150000
#define DIM     64
#define NNZ     2000000
#define NHOPS   3
#define NBLK_SCAN ((NTOT + 255) / 256)   // 587
#define NOCT    8
#define OCT_ROWS (NTOT / NOCT)           // 18750

// ---------------- Threefry-2x32, 20 rounds (JAX-compatible) ----------------
__host__ __device__ inline void tf2x32(uint32_t k0, uint32_t k1,
                                       uint32_t x0, uint32_t x1,
                                       uint32_t& o0, uint32_t& o1) {
  uint32_t ks2 = k0 ^ k1 ^ 0x1BD11BDAu;
  x0 += k0; x1 += k1;
#define ROTL(x,r) (((x) << (r)) | ((x) >> (32 - (r))))
#define RND(r) { x0 += x1; x1 = ROTL(x1, r); x1 ^= x0; }
  RND(13) RND(15) RND(26) RND(6)
  x0 += k1;  x1 += ks2 + 1u;
  RND(17) RND(29) RND(16) RND(24)
  x0 += ks2; x1 += k0 + 2u;
  RND(13) RND(15) RND(26) RND(6)
  x0 += k0;  x1 += k1 + 3u;
  RND(17) RND(29) RND(16) RND(24)
  x0 += k1;  x1 += ks2 + 4u;
  RND(13) RND(15) RND(26) RND(6)
  x0 += ks2; x1 += k0 + 5u;
  o0 = x0; o1 = x1;
#undef RND
#undef ROTL
}

__device__ inline float tf_uniform(uint32_t k0, uint32_t k1, uint32_t idx) {
  uint32_t b1, b2;
  tf2x32(k0, k1, 0u, idx, b1, b2);
  uint32_t bits = b1 ^ b2;
  return __uint_as_float((bits >> 9) | 0x3f800000u) - 1.0f;
}

__device__ inline uint32_t keep_bits(uint32_t e,
                                     uint32_t e00, uint32_t e01,
                                     uint32_t e10, uint32_t e11,
                                     uint32_t e20, uint32_t e21) {
  uint32_t kb = 0u;                              // match reference fp exactly
  if (0.5f + tf_uniform(e00, e01, e) >= 1.0f) kb |= 1u;
  if (0.5f + tf_uniform(e10, e11, e) >= 1.0f) kb |= 2u;
  if (0.5f + tf_uniform(e20, e21, e) >= 1.0f) kb |= 4u;
  return kb;
}

// ---------------- kernels ----------------
// out layout: [n][hop(0..3)][d] float32. Row stride = 256 floats.

// hop0 = concat(user,item). Hop slices 1..3 are fully written by k_spmm_seg.
__global__ __launch_bounds__(256) void k_init(const float4* __restrict__ user,
                                              const float4* __restrict__ item,
                                              float4* __restrict__ out) {
  int idx = blockIdx.x * 256 + threadIdx.x;      // over NTOT*16 float4s
  if (idx >= NTOT * 16) return;
  int n = idx >> 4;
  float4 v = (n < N_USERS) ? user[idx] : item[idx - N_USERS * 16];
  out[(size_t)n * 64 + (idx & 15)] = v;
}

// RNG pass: compute per-edge keep bits (all 3 hops), store them, and
// histogram row degrees counting ONLY edges kept in >=1 hop.
__global__ __launch_bounds__(256) void k_hist(const int* __restrict__ rows,
                                              uint32_t* __restrict__ cnt,
                                              uint8_t* __restrict__ kbits,
                                              uint32_t e00, uint32_t e01,
                                              uint32_t e10, uint32_t e11,
                                              uint32_t e20, uint32_t e21) {
  int e = blockIdx.x * 256 + threadIdx.x;
  if (e >= NNZ) return;
  uint32_t kb = keep_bits((uint32_t)e, e00, e01, e10, e11, e20, e21);
  kbits[e] = (uint8_t)kb;
  if (kb) atomicAdd(&cnt[rows[e]], 1u);
}

// block-level exclusive scan (256-wide) + block totals
__global__ __launch_bounds__(256) void k_scan1(const uint32_t* __restrict__ cnt,
                                               uint32_t* __restrict__ strt,
                                               uint32_t* __restrict__ part) {
  __shared__ uint32_t s[256];
  int t = threadIdx.x;
  int i = blockIdx.x * 256 + t;
  uint32_t x = (i < NTOT) ? cnt[i] : 0u;
  s[t] = x; __syncthreads();
  for (int off = 1; off < 256; off <<= 1) {
    uint32_t y = (t >= off) ? s[t - off] : 0u;
    __syncthreads();
    s[t] += y;
    __syncthreads();
  }
  if (i < NTOT) strt[i] = s[t] - x;              // exclusive
  if (t == 255) part[blockIdx.x] = s[255];       // block total
}

// exclusive scan of the 587 block totals (single block)
__global__ __launch_bounds__(1024) void k_scan2(uint32_t* __restrict__ part) {
  __shared__ uint32_t s[1024];
  int t = threadIdx.x;
  uint32_t x = (t < NBLK_SCAN) ? part[t] : 0u;
  s[t] = x; __syncthreads();
  for (int off = 1; off < 1024; off <<= 1) {
    uint32_t y = (t >= off) ? s[t - off] : 0u;
    __syncthreads();
    s[t] += y;
    __syncthreads();
  }
  if (t < NBLK_SCAN) part[t] = s[t] - x;         // exclusive
}

// add block offsets; init per-row scatter cursors
__global__ __launch_bounds__(256) void k_scan3(uint32_t* __restrict__ strt,
                                               const uint32_t* __restrict__ part,
                                               uint32_t* __restrict__ cur) {
  int i = blockIdx.x * 256 + threadIdx.x;
  if (i >= NTOT) return;
  uint32_t v = strt[i] + part[i >> 8];
  strt[i] = v;
  cur[i] = v;
}

// XCD-partitioned scatter: block (bid&7) handles only rows in its octant,
// so each rec line is written by ONE XCD's L2 -> full-line writeback.
//   rec.x = col<<3 | keep0 | keep1<<1 | keep2<<2,  rec.y = bits(val*2)
__global__ __launch_bounds__(256) void k_scatter(const float* __restrict__ vals,
                                                 const int* __restrict__ rows,
                                                 const int* __restrict__ cols,
                                                 const uint8_t* __restrict__ kbits,
                                                 uint32_t* __restrict__ cur,
                                                 uint2* __restrict__ rec) {
  int e = (blockIdx.x >> 3) * 256 + threadIdx.x;
  if (e >= NNZ) return;
  int oct = blockIdx.x & 7;                      // presumed XCD (round-robin)
  int row = rows[e];
  if (row / OCT_ROWS != oct) return;
  uint32_t kb = kbits[e];
  if (!kb) return;
  float val2 = vals[e] * 2.0f;                   // 1/(1-EDGE_RATE) = 2
  uint32_t j = atomicAdd(&cur[row], 1u);
  rec[j] = make_uint2(((uint32_t)cols[e] << 3) | kb, __float_as_uint(val2));
}

// segmented SpMM: one WAVE per 4 rows; 16 lanes x float4 per row.
// 4 independent row-chains x unroll-4 = up to 16 outstanding gathers/wave.
// Dropped-this-hop edges gather row 0 (L1-hot) with v=0. Fused message dropout.
__global__ __launch_bounds__(256) void k_spmm_seg(const uint32_t* __restrict__ strt,
                                                  const uint32_t* __restrict__ cnt,
                                                  const uint2* __restrict__ rec,
                                                  float* __restrict__ out,
                                                  int hop, uint32_t km0, uint32_t km1) {
  int wave = (blockIdx.x * 256 + threadIdx.x) >> 6;
  int lane = threadIdx.x & 63;
  int g = lane >> 4;                 // row subgroup 0..3
  int q = lane & 15;                 // float4 chunk 0..15
  int row = wave * 4 + g;
  if (row >= NTOT) return;
  uint32_t s = strt[row];
  uint32_t e = s + cnt[row];
  const uint32_t mask = 1u << hop;
  // src row c, float4 chunk q lives at float4 index c*64 + hop*16 + q
  const float4* srcb = (const float4*)out + (size_t)hop * 16 + q;
  float4 a0 = {0.f,0.f,0.f,0.f}, a1 = a0, a2 = a0, a3 = a0;
  uint32_t j = s;
  for (; j + 4 <= e; j += 4) {
    uint2 r0 = rec[j], r1 = rec[j + 1], r2 = rec[j + 2], r3 = rec[j + 3];
    bool k0 = (r0.x & mask) != 0u, k1 = (r1.x & mask) != 0u;
    bool k2 = (r2.x & mask) != 0u, k3 = (r3.x & mask) != 0u;
    size_t c0 = k0 ? (size_t)(r0.x >> 3) * 64 : 0;
    size_t c1 = k1 ? (size_t)(r1.x >> 3) * 64 : 0;
    size_t c2 = k2 ? (size_t)(r2.x >> 3) * 64 : 0;
    size_t c3 = k3 ? (size_t)(r3.x >> 3) * 64 : 0;
    float4 s0 = srcb[c0], s1 = srcb[c1], s2 = srcb[c2], s3 = srcb[c3];
    float v0 = k0 ? __uint_as_float(r0.y) : 0.f;
    float v1 = k1 ? __uint_as_float(r1.y) : 0.f;
    float v2 = k2 ? __uint_as_float(r2.y) : 0.f;
    float v3 = k3 ? __uint_as_float(r3.y) : 0.f;
    a0.x += v0 * s0.x; a0.y += v0 * s0.y; a0.z += v0 * s0.z; a0.w += v0 * s0.w;
    a1.x += v1 * s1.x; a1.y += v1 * s1.y; a1.z += v1 * s1.z; a1.w += v1 * s1.w;
    a2.x += v2 * s2.x; a2.y += v2 * s2.y; a2.z += v2 * s2.z; a2.w += v2 * s2.w;
    a3.x += v3 * s3.x; a3.y += v3 * s3.y; a3.z += v3 * s3.z; a3.w += v3 * s3.w;
  }
  for (; j < e; ++j) {
    uint2 r = rec[j];
    if (r.x & mask) {
      float v = __uint_as_float(r.y);
      float4 sv = srcb[(size_t)(r.x >> 3) * 64];
      a0.x += v * sv.x; a0.y += v * sv.y; a0.z += v * sv.z; a0.w += v * sv.w;
    }
  }
  float4 acc;
  acc.x = (a0.x + a1.x) + (a2.x + a3.x);
  acc.y = (a0.y + a1.y) + (a2.y + a3.y);
  acc.z = (a0.z + a1.z) + (a2.z + a3.z);
  acc.w = (a0.w + a1.w) + (a2.w + a3.w);
  // message dropout (inverted, keep iff u < 0.9), flat index over (NTOT, DIM)
  uint32_t base = (uint32_t)(row * 64 + q * 4);
  float u0 = tf_uniform(km0, km1, base + 0u);
  float u1 = tf_uniform(km0, km1, base + 1u);
  float u2 = tf_uniform(km0, km1, base + 2u);
  float u3 = tf_uniform(km0, km1, base + 3u);
  const float sc = (float)(1.0 / 0.9);
  acc.x = (u0 < 0.9f) ? acc.x * sc : 0.0f;
  acc.y = (u1 < 0.9f) ? acc.y * sc : 0.0f;
  acc.z = (u2 < 0.9f) ? acc.z * sc : 0.0f;
  acc.w = (u3 < 0.9f) ? acc.w * sc : 0.0f;
  ((float4*)(out + ((size_t)row * 4 + hop + 1) * 64))[q] = acc;
}

// ---------------- launch ----------------
extern "C" void kernel_launch(void* const* d_in, const int* in_sizes, int n_in,
                              void* d_out, int out_size, void* d_ws, size_t ws_size,
                              hipStream_t stream) {
  const float* user = (const float*)d_in[0];
  const float* item = (const float*)d_in[1];
  const float* vals = (const float*)d_in[2];
  const int*   rows = (const int*)d_in[3];
  const int*   cols = (const int*)d_in[4];
  float* out = (float*)d_out;

  // workspace layout (~20 MB)
  uint32_t* cnt   = (uint32_t*)d_ws;         // NTOT
  uint32_t* strt  = cnt + NTOT;              // NTOT
  uint32_t* cur   = strt + NTOT;             // NTOT
  uint32_t* part  = cur + NTOT;              // 1024 (pad)
  uint2*    rec   = (uint2*)(part + 1024);   // <= NNZ * 8B
  uint8_t*  kbits = (uint8_t*)(rec + NNZ);   // NNZ bytes

  // host-side key schedule: key(42) -> per-hop (dkey, ke, km)
  uint32_t k0 = 0u, k1 = 42u;
  uint32_t ke[NHOPS][2], km[NHOPS][2];
  for (int h = 0; h < NHOPS; ++h) {
    uint32_t nk0, nk1;
    tf2x32(k0, k1, 0u, 0u, nk0, nk1);
    tf2x32(k0, k1, 0u, 1u, ke[h][0], ke[h][1]);
    tf2x32(k0, k1, 0u, 2u, km[h][0], km[h][1]);
    k0 = nk0; k1 = nk1;
  }

  hipMemsetAsync(cnt, 0, NTOT * sizeof(uint32_t), stream);
  k_hist<<<(NNZ + 255) / 256, 256, 0, stream>>>(rows, cnt, kbits,
                                                ke[0][0], ke[0][1],
                                                ke[1][0], ke[1][1],
                                                ke[2][0], ke[2][1]);
  k_scan1<<<NBLK_SCAN, 256, 0, stream>>>(cnt, strt, part);
  k_scan2<<<1, 1024, 0, stream>>>(part);
  k_scan3<<<NBLK_SCAN, 256, 0, stream>>>(strt, part, cur);
  k_scatter<<<NOCT * ((NNZ + 255) / 256), 256, 0, stream>>>(vals, rows, cols,
                                                            kbits, cur, rec);
  k_init<<<(NTOT * 16 + 255) / 256, 256, 0, stream>>>(
      (const float4*)user, (const float4*)item, (float4*)out);

  for (int h = 0; h < NHOPS; ++h) {
    k_spmm_seg<<<((NTOT + 3) / 4 * 64 + 255) / 256, 256, 0, stream>>>(
        strt, cnt, rec, out, h, km[h][0], km[h][1]);
  }
}